// Round 1
// baseline (14.468 us; speedup 1.0000x reference)
//
#include <hip/hip_runtime.h>

// StatisticalSMA: per (batch b, channel c) take the last 5 timesteps of
// x[b, :, c], then 96 steps of: f = mean(window); window = shift+append(f).
// Output out[b, t, c], shape (2048, 96, 64) fp32.
//
// One thread per (b, c) sequence: 2048*64 = 131072 threads.
// thread = b*64 + c  -> lane index == channel -> every global load/store is
// 64-lane contiguous (256 B per wave transaction). Rolling window lives in
// 5 registers; full unroll removes the shift moves.

#define SMA_B 2048
#define SMA_S 512
#define SMA_C 64
#define SMA_W 5
#define SMA_T 96

__global__ __launch_bounds__(256) void StatisticalSMA_kernel(
    const float* __restrict__ x, float* __restrict__ out) {
    int tid = blockIdx.x * blockDim.x + threadIdx.x;   // 0 .. 131071
    int b = tid >> 6;          // batch
    int c = tid & 63;          // channel (lane-contiguous)

    // window start: x[b, S-W .. S-1, c]
    const float* xp = x + (size_t)b * (SMA_S * SMA_C) + (SMA_S - SMA_W) * SMA_C + c;
    float w0 = xp[0 * SMA_C];
    float w1 = xp[1 * SMA_C];
    float w2 = xp[2 * SMA_C];
    float w3 = xp[3 * SMA_C];
    float w4 = xp[4 * SMA_C];

    float* op = out + (size_t)b * (SMA_T * SMA_C) + c;
    #pragma unroll
    for (int t = 0; t < SMA_T; ++t) {
        float f = (w0 + w1 + w2 + w3 + w4) * 0.2f;
        op[t * SMA_C] = f;
        w0 = w1; w1 = w2; w2 = w3; w3 = w4; w4 = f;
    }
}

extern "C" void kernel_launch(void* const* d_in, const int* in_sizes, int n_in,
                              void* d_out, int out_size, void* d_ws, size_t ws_size,
                              hipStream_t stream) {
    const float* x = (const float*)d_in[0];
    float* out = (float*)d_out;
    const int total = SMA_B * SMA_C;           // 131072 threads
    const int block = 256;
    const int grid = total / block;            // 512 blocks
    StatisticalSMA_kernel<<<grid, block, 0, stream>>>(x, out);
}